// Round 12
// baseline (134.172 us; speedup 1.0000x reference)
//
#include <hip/hip_runtime.h>
#include <hip/hip_cooperative_groups.h>
#include <cstdint>
#include <cstddef>

namespace cg = cooperative_groups;

#define B_   512
#define V_   6890
#define VP   6912
#define NJ   24
#define KF   224
#define NP   46
#define NVT  432
#define NBT  32
#define NKT  7

typedef float f32x4 __attribute__((ext_vector_type(4)));
typedef short s16x8 __attribute__((ext_vector_type(8)));

__device__ __forceinline__ unsigned short f2bf(float f) {
  unsigned int u = __float_as_uint(f);
  u = (u + 0x7FFFu + ((u >> 16) & 1u)) >> 16;
  return (unsigned short)u;
}
__device__ __forceinline__ float bf2f(unsigned short h) {
  return __uint_as_float(((unsigned int)h) << 16);
}

__constant__ float c_axes[47][3] = {
  { 0.f, 0.f, 1.f}, { 1.f, 0.f, 0.f}, { 0.f, 1.f, 0.f},
  { 0.f, 0.f, 1.f}, { 1.f, 0.f, 0.f}, { 0.f, 1.f, 0.f},
  { 0.f, 0.f,-1.f},
  {-0.10501402f,-0.17402183f, 0.97912636f},
  { 0.78718019f, 0.60474702f,-0.12094817f},
  { 0.58095459f, 0.00000217f,-0.81393598f},
  { 0.f, 0.f, 1.f}, {-1.f, 0.f, 0.f}, { 0.f,-1.f, 0.f},
  { 0.f, 0.f,-1.f},
  {-0.10501402f,-0.17402183f, 0.97912636f},
  {-0.78718019f,-0.60474702f,-0.12094817f},
  {-0.58095459f, 0.00000217f,-0.81393598f},
  { 1.f, 0.f, 0.f}, { 0.f, 0.f, 1.f}, { 0.f, 1.f, 0.f},
  { 1.f, 0.f, 0.f}, { 0.f, 0.f, 1.f}, { 0.f, 1.f, 0.f},
  { 1.f, 0.f, 0.f}, { 0.f, 0.f, 1.f}, { 0.f, 1.f, 0.f},
  { 0.f, 1.f, 0.f}, { 0.f, 0.f,-1.f}, {-1.f, 0.f, 0.f},
  { 1.f, 0.f, 0.f}, { 0.f, 1.f, 0.f}, { 0.f, 0.f, 1.f},
  { 0.0494f, 0.0366f, 0.99810825f},
  {-0.01716099f, 0.99266564f,-0.11966796f},
  { 1.f, 0.f, 0.f}, { 0.f, 0.f,-1.f},
  { 0.f, 1.f, 0.f}, { 0.f, 0.f, 1.f}, { 1.f, 0.f, 0.f},
  { 1.f, 0.f, 0.f}, { 0.f, 1.f, 0.f}, { 0.f, 0.f, 1.f},
  {-0.0494f,-0.0366f, 0.99810825f},
  { 0.01716099f,-0.99266564f,-0.11966796f},
  {-1.f, 0.f, 0.f}, { 0.f, 0.f,-1.f},
  { 0.f, 0.f, 0.f}
};
__constant__ int c_ridx[24][3] = {
  {0,1,2},{3,4,5},{6,46,46},{7,46,46},{8,46,46},{9,46,46},
  {10,11,12},{13,46,46},{14,46,46},{15,46,46},{16,46,46},
  {17,18,19},{20,21,22},{23,24,25},{26,27,28},{29,30,31},
  {32,46,46},{33,46,46},{34,35,46},{36,37,38},{39,40,41},
  {42,46,46},{43,46,46},{44,45,46}
};
__constant__ int c_par[24] = {-1,0,1,2,3,4,0,6,7,8,9,0,11,12,12,14,15,16,17,12,19,20,21,22};

__device__ __forceinline__ void mm3(const float* A, const float* Bm, float* C) {
#pragma unroll
  for (int i = 0; i < 3; ++i)
#pragma unroll
    for (int j = 0; j < 3; ++j)
      C[i*3+j] = A[i*3+0]*Bm[0+j] + A[i*3+1]*Bm[3+j] + A[i*3+2]*Bm[6+j];
}
__device__ __forceinline__ void mm3_bt(const float* A, const float* Bm, float* C) {
#pragma unroll
  for (int i = 0; i < 3; ++i)
#pragma unroll
    for (int j = 0; j < 3; ++j)
      C[i*3+j] = A[i*3+0]*Bm[j*3+0] + A[i*3+1]*Bm[j*3+1] + A[i*3+2]*Bm[j*3+2];
}

// ---- single cooperative kernel, 216 blocks (1/CU co-resident) x 512 thr ----
// P1 prep | grid.sync | P2 pose+frag | grid.sync | P3 MFMA (2 tile-units/block)
__global__ __launch_bounds__(512) void k_all(
    const float* __restrict__ posed, const float* __restrict__ sd,
    const float* __restrict__ vt,    const float* __restrict__ sw,
    const float* __restrict__ jreg,  const float* __restrict__ poses,
    const float* __restrict__ betas, const float* __restrict__ trans,
    const float* __restrict__ apose, const float* __restrict__ pjr,
    unsigned short* __restrict__ pdm, unsigned short* __restrict__ fmf,
    unsigned short* __restrict__ smf, unsigned short* __restrict__ mmf,
    float* __restrict__ jts_part,     float* __restrict__ out)
{
  cg::grid_group grid = cg::this_grid();
  const int t    = threadIdx.x;
  const int lane = t & 63;
  const int w    = t >> 6;                       // 0..7
  const int gw   = blockIdx.x * 8 + w;           // 0..1727

  __shared__ float ldsW[8][927];   // per wave: [0,423) RdG; [423,639) Rj; [639,855) Rl; [855,927) jl
  __shared__ float jts_s[792];

  // ================= P1: static prep =================
  if (gw < 1536) {
    for (int u = gw; u < 9936; u += 1536) {
      if (u < 9072) {                            // pdm tile: u = c*3024 + vtg*7 + kt
        int kt  = u % 7;
        int vtg = (u / 7) % NVT;
        int c   = u / 3024;
        int v   = vtg*16 + (lane & 15);
        int kb  = kt*32 + (lane >> 4)*8;
        unsigned short vals[8];
#pragma unroll
        for (int j = 0; j < 8; ++j) {
          int k = kb + j;
          float f = 0.f;
          if (v < V_) {
            if (k < 207)       f = posed[(v*3 + c)*207 + k];
            else if (k < 217)  f = sd[(v*3 + c)*10 + (k - 207)];
            else if (k == 217) f = vt[v*3 + c];
          }
          vals[j] = f2bf(f);
        }
        *(uint4*)(pdm + (size_t)u*512 + lane*8) = *(const uint4*)vals;
      } else {                                   // smf tile
        int u2   = u - 9072;
        int slot = u2 & 1;
        int vtg  = u2 >> 1;
        int v  = vtg*16 + (lane & 15);
        int j0 = (lane >> 4) * 8;
        unsigned short vals[8];
#pragma unroll
        for (int jj = 0; jj < 8; ++jj) {
          int j = j0 + jj;
          float s = (v < V_ && j < NJ) ? sw[v*NJ + j] : 0.f;
          unsigned short hi = f2bf(s);
          vals[jj] = slot ? f2bf(s - bf2f(hi)) : hi;
        }
        *(uint4*)(smf + (size_t)u2*512 + lane*8) = *(const uint4*)vals;
      }
    }
  } else {
    // jts partials: 192 waves, one (j,chunk) each; intra-wave shuffle reduce
    int unit  = gw - 1536;                       // 0..191
    int j     = unit % 24;
    int chunk = unit / 24;
    int v0 = chunk * 864;
    int v1 = (v0 + 864 < V_) ? v0 + 864 : V_;
    float acc[33];
#pragma unroll
    for (int i = 0; i < 33; ++i) acc[i] = 0.f;
    for (int v = v0 + lane; v < v1; v += 64) {
      float wgt = jreg[j*V_ + v];
#pragma unroll
      for (int c = 0; c < 3; ++c) {
        acc[c*11] += wgt * vt[v*3 + c];
        const float* s = sd + (v*3 + c)*10;
#pragma unroll
        for (int k = 0; k < 10; ++k) acc[c*11 + 1 + k] += wgt * s[k];
      }
    }
#pragma unroll
    for (int i = 0; i < 33; ++i)
#pragma unroll
      for (int o = 32; o > 0; o >>= 1) acc[i] += __shfl_xor(acc[i], o, 64);
    if (lane == 0) {
#pragma unroll
      for (int i = 0; i < 33; ++i) jts_part[chunk*792 + j*33 + i] = acc[i];
    }
  }

  grid.sync();

  // ================= P2: pose math, one batch per wave (first 512 waves) =================
  for (int i = t; i < 792; i += 512) {
    float s = 0.f;
#pragma unroll
    for (int c8 = 0; c8 < 8; ++c8) s += jts_part[c8*792 + i];
    jts_s[i] = s;
  }
  __syncthreads();

  const bool live = (gw < B_);
  const int  b    = live ? gw : (B_ - 1);        // dummy batch keeps barriers uniform
  float* RdG = &ldsW[w][0];
  float* Rj  = &ldsW[w][423];
  float* Rl  = &ldsW[w][639];
  float* jl  = &ldsW[w][855];

  if (lane < 47) {
    float q  = (lane < NP) ? poses[b*NP + lane] : 0.f;
    float ax = c_axes[lane][0], ay = c_axes[lane][1], az = c_axes[lane][2];
    float s = sinf(q), cq = cosf(q);
    float u = 1.f - cq;
    RdG[lane*9+0] = u*ax*ax + cq;   RdG[lane*9+1] = u*ax*ay - s*az; RdG[lane*9+2] = u*ax*az + s*ay;
    RdG[lane*9+3] = u*ax*ay + s*az; RdG[lane*9+4] = u*ay*ay + cq;   RdG[lane*9+5] = u*ay*az - s*ax;
    RdG[lane*9+6] = u*ax*az - s*ay; RdG[lane*9+7] = u*ay*az + s*ax; RdG[lane*9+8] = u*az*az + cq;
  }
  if (lane < NJ) {
    const float* jr = jts_s + lane*33;
#pragma unroll
    for (int c = 0; c < 3; ++c) {
      float a = jr[c*11];
#pragma unroll
      for (int k = 0; k < 10; ++k) a += jr[c*11 + 1 + k] * betas[b*10 + k];
      jl[lane*3 + c] = a;
    }
  }
  __syncthreads();
  if (lane < NJ) {
    float C1[9], C2[9];
    const int r0 = c_ridx[lane][0], r1 = c_ridx[lane][1], r2 = c_ridx[lane][2];
    mm3(&RdG[r0*9], &RdG[r1*9], C1);
    mm3(C1, &RdG[r2*9], C2);                     // Rj
#pragma unroll
    for (int e = 0; e < 9; ++e) Rj[lane*9+e] = C2[e];
    float P[9], Ap[9];
#pragma unroll
    for (int e = 0; e < 9; ++e) { P[e] = pjr[lane*9 + e]; Ap[e] = apose[lane*9 + e]; }
    mm3(P, C2, C1);
    mm3_bt(C1, P, C2);
    mm3(Ap, C2, C1);
#pragma unroll
    for (int e = 0; e < 9; ++e) Rl[lane*9+e] = C1[e];
  }
  __syncthreads();                               // RdG dead -> reuse as G[24][12]
  if (lane == 0) {
    float* G = RdG;
#pragma unroll
    for (int e = 0; e < 9; ++e) G[e] = Rl[e];
    G[9] = jl[0]; G[10] = jl[1]; G[11] = jl[2];
    for (int j = 1; j < NJ; ++j) {
      int p = c_par[j];
      float R[9];
      mm3(&G[p*12], &Rl[j*9], R);
#pragma unroll
      for (int e = 0; e < 9; ++e) G[j*12+e] = R[e];
      float d0 = jl[j*3+0]-jl[p*3+0], d1 = jl[j*3+1]-jl[p*3+1], d2 = jl[j*3+2]-jl[p*3+2];
      G[j*12+ 9] = G[p*12+ 9] + G[p*12+0]*d0 + G[p*12+1]*d1 + G[p*12+2]*d2;
      G[j*12+10] = G[p*12+10] + G[p*12+3]*d0 + G[p*12+4]*d1 + G[p*12+5]*d2;
      G[j*12+11] = G[p*12+11] + G[p*12+6]*d0 + G[p*12+7]*d1 + G[p*12+8]*d2;
    }
  }
  __syncthreads();
  if (lane < NJ) {                               // A_t in place (+trans)
    float* G = RdG;
    float jx = jl[lane*3+0], jy = jl[lane*3+1], jz = jl[lane*3+2];
    float tx = trans[b*3+0], ty = trans[b*3+1], tz = trans[b*3+2];
    float a0 = G[lane*12+ 9] - (G[lane*12+0]*jx + G[lane*12+1]*jy + G[lane*12+2]*jz) + tx;
    float a1 = G[lane*12+10] - (G[lane*12+3]*jx + G[lane*12+4]*jy + G[lane*12+5]*jz) + ty;
    float a2 = G[lane*12+11] - (G[lane*12+6]*jx + G[lane*12+7]*jy + G[lane*12+8]*jz) + tz;
    G[lane*12+ 9] = a0; G[lane*12+10] = a1; G[lane*12+11] = a2;
  }
  __syncthreads();

  if (live) {
    const int bt  = b >> 4;
    const int bl2 = b & 15;
    const float* G = RdG;
    for (int task = lane; task < 124; task += 64) {
      if (task < 28) {                           // fmf
        int kt = task >> 2, h = task & 3;
        int ln = bl2 + 16*h;
        unsigned short vals[8];
#pragma unroll
        for (int j = 0; j < 8; ++j) {
          int k = kt*32 + h*8 + j;
          float val;
          if (k < 207) {
            int jj = k / 9 + 1, e = k % 9;
            val = Rj[jj*9+e] - ((e == 0 || e == 4 || e == 8) ? 1.f : 0.f);
          } else if (k < 217) val = betas[b*10 + (k - 207)];
          else if (k == 217)  val = 1.f;
          else                val = 0.f;
          vals[j] = f2bf(val);
        }
        *(uint4*)(fmf + ((size_t)bt*NKT + kt)*512 + ln*8) = *(const uint4*)vals;
      } else {                                   // mmf
        int m = task - 28;
        int e = m >> 3;
        int r = m & 7;
        int slot = r >> 2;
        int h    = r & 3;
        int ln = bl2 + 16*h;
        int j0 = h*8;
        unsigned short vals[8];
#pragma unroll
        for (int jj = 0; jj < 8; ++jj) {
          int j = j0 + jj;
          float f = (j < NJ) ? G[j*12 + e] : 0.f;
          unsigned short hi = f2bf(f);
          vals[jj] = slot ? f2bf(f - bf2f(hi)) : hi;
        }
        *(uint4*)(mmf + (((size_t)e*NBT + bt)*2 + slot)*512 + ln*8) = *(const uint4*)vals;
      }
    }
  }

  grid.sync();

  // ================= P3: GEMM1 + GEMM2 + combine; 2 logical tile-units per block =================
  const int swz = (blockIdx.x & 7) * 27 + (blockIdx.x >> 3);   // bijective, 216 = 8*27
#pragma unroll 1
  for (int unit = 0; unit < 2; ++unit) {
    const int wg   = swz*2 + unit;               // 0..431
    const int bt_blk = wg & 7;
    const int vt_blk = wg >> 3;
    const int wv   = w >> 1, wb = w & 1;
    const int vtg0 = vt_blk*8 + wv*2;
    const int btg0 = bt_blk*4 + wb*2;

    s16x8 sh[2], sl[2];
#pragma unroll
    for (int vs = 0; vs < 2; ++vs) {
      sh[vs] = *(const s16x8*)(smf + ((size_t)(vtg0+vs)*2 + 0)*512 + lane*8);
      sl[vs] = *(const s16x8*)(smf + ((size_t)(vtg0+vs)*2 + 1)*512 + lane*8);
    }

    f32x4 acc1[2][2][3];
#pragma unroll
    for (int vs = 0; vs < 2; ++vs)
#pragma unroll
      for (int bs = 0; bs < 2; ++bs)
#pragma unroll
        for (int c = 0; c < 3; ++c) acc1[vs][bs][c] = (f32x4){0.f,0.f,0.f,0.f};

#pragma unroll 1
    for (int kt = 0; kt < NKT; ++kt) {
      s16x8 fa[2], pb[2][3];
#pragma unroll
      for (int bs = 0; bs < 2; ++bs)
        fa[bs] = *(const s16x8*)(fmf + ((size_t)(btg0+bs)*NKT + kt)*512 + lane*8);
#pragma unroll
      for (int vs = 0; vs < 2; ++vs)
#pragma unroll
        for (int c = 0; c < 3; ++c)
          pb[vs][c] = *(const s16x8*)(pdm + (((size_t)c*NVT + vtg0+vs)*NKT + kt)*512 + lane*8);
#pragma unroll
      for (int vs = 0; vs < 2; ++vs)
#pragma unroll
        for (int bs = 0; bs < 2; ++bs)
#pragma unroll
          for (int c = 0; c < 3; ++c)
            acc1[vs][bs][c] = __builtin_amdgcn_mfma_f32_16x16x32_bf16(fa[bs], pb[vs][c], acc1[vs][bs][c], 0, 0, 0);
    }

    f32x4 vo[2][2][3];
#pragma unroll
    for (int vs = 0; vs < 2; ++vs)
#pragma unroll
      for (int bs = 0; bs < 2; ++bs)
#pragma unroll
        for (int m = 0; m < 3; ++m) vo[vs][bs][m] = (f32x4){0.f,0.f,0.f,0.f};

#pragma unroll
    for (int e = 0; e < 12; ++e) {
      s16x8 mh[2], ml[2];
#pragma unroll
      for (int bs = 0; bs < 2; ++bs) {
        mh[bs] = *(const s16x8*)(mmf + (((size_t)e*NBT + btg0+bs)*2 + 0)*512 + lane*8);
        ml[bs] = *(const s16x8*)(mmf + (((size_t)e*NBT + btg0+bs)*2 + 1)*512 + lane*8);
      }
#pragma unroll
      for (int vs = 0; vs < 2; ++vs)
#pragma unroll
        for (int bs = 0; bs < 2; ++bs) {
          f32x4 tmp = (f32x4){0.f,0.f,0.f,0.f};
          tmp = __builtin_amdgcn_mfma_f32_16x16x32_bf16(mh[bs], sh[vs], tmp, 0, 0, 0);
          tmp = __builtin_amdgcn_mfma_f32_16x16x32_bf16(ml[bs], sh[vs], tmp, 0, 0, 0);
          tmp = __builtin_amdgcn_mfma_f32_16x16x32_bf16(mh[bs], sl[vs], tmp, 0, 0, 0);
          if (e < 9) vo[vs][bs][e/3] += tmp * acc1[vs][bs][e%3];
          else       vo[vs][bs][e-9] += tmp;
        }
    }

#pragma unroll
    for (int vs = 0; vs < 2; ++vs) {
      const int v = (vtg0+vs)*16 + (lane & 15);
      if (v < V_) {
#pragma unroll
        for (int bs = 0; bs < 2; ++bs) {
          const int b0 = (btg0+bs)*16 + (lane >> 4)*4;
#pragma unroll
          for (int q = 0; q < 4; ++q) {
            float* op = out + ((size_t)(b0 + q)*V_ + v)*3;
            op[0] = vo[vs][bs][0][q];
            op[1] = vo[vs][bs][1][q];
            op[2] = vo[vs][bs][2][q];
          }
        }
      }
    }
  }
}

extern "C" void kernel_launch(void* const* d_in, const int* in_sizes, int n_in,
                              void* d_out, int out_size, void* d_ws, size_t ws_size,
                              hipStream_t stream) {
  (void)in_sizes; (void)n_in; (void)out_size; (void)ws_size;
  const float* betas      = (const float*)d_in[0];
  const float* poses      = (const float*)d_in[1];
  const float* trans      = (const float*)d_in[2];
  const float* v_template = (const float*)d_in[3];
  const float* shapedirs  = (const float*)d_in[4];
  const float* posedirs   = (const float*)d_in[5];
  const float* jreg       = (const float*)d_in[6];
  const float* skinw      = (const float*)d_in[7];
  const float* apose      = (const float*)d_in[8];
  const float* pjr        = (const float*)d_in[9];
  float* out = (float*)d_out;
  float* ws  = (float*)d_ws;

  unsigned short* pdm = (unsigned short*)ws;              // 9072*512 u16 = 2,322,432 f32
  unsigned short* fmf = (unsigned short*)(ws + 2322432);  // 224*512  u16
  unsigned short* smf = (unsigned short*)(ws + 2379776);  // 864*512  u16
  unsigned short* mmf = (unsigned short*)(ws + 2600960);  // 768*512  u16
  float* jts_part = ws + 2797568;                         // 8*792

  void* kargs[] = {
    (void*)&posedirs, (void*)&shapedirs, (void*)&v_template, (void*)&skinw,
    (void*)&jreg, (void*)&poses, (void*)&betas, (void*)&trans,
    (void*)&apose, (void*)&pjr,
    (void*)&pdm, (void*)&fmf, (void*)&smf, (void*)&mmf,
    (void*)&jts_part, (void*)&out
  };
  hipLaunchCooperativeKernel((const void*)k_all, dim3(216), dim3(512),
                             kargs, 0, stream);
}

// Round 13
// 59.555 us; speedup vs baseline: 2.2529x; 2.2529x over previous
//
#include <hip/hip_runtime.h>
#include <cstdint>
#include <cstddef>

#define B_   512
#define V_   6890
#define VP   6912
#define NJ   24
#define KF   224
#define NP   46
#define NVT  432
#define NBT  32
#define NKT  7

typedef float f32x4 __attribute__((ext_vector_type(4)));
typedef short s16x8 __attribute__((ext_vector_type(8)));

__device__ __forceinline__ unsigned short f2bf(float f) {
  unsigned int u = __float_as_uint(f);
  u = (u + 0x7FFFu + ((u >> 16) & 1u)) >> 16;
  return (unsigned short)u;
}
__device__ __forceinline__ float bf2f(unsigned short h) {
  return __uint_as_float(((unsigned int)h) << 16);
}

__constant__ float c_axes[47][3] = {
  { 0.f, 0.f, 1.f}, { 1.f, 0.f, 0.f}, { 0.f, 1.f, 0.f},
  { 0.f, 0.f, 1.f}, { 1.f, 0.f, 0.f}, { 0.f, 1.f, 0.f},
  { 0.f, 0.f,-1.f},
  {-0.10501402f,-0.17402183f, 0.97912636f},
  { 0.78718019f, 0.60474702f,-0.12094817f},
  { 0.58095459f, 0.00000217f,-0.81393598f},
  { 0.f, 0.f, 1.f}, {-1.f, 0.f, 0.f}, { 0.f,-1.f, 0.f},
  { 0.f, 0.f,-1.f},
  {-0.10501402f,-0.17402183f, 0.97912636f},
  {-0.78718019f,-0.60474702f,-0.12094817f},
  {-0.58095459f, 0.00000217f,-0.81393598f},
  { 1.f, 0.f, 0.f}, { 0.f, 0.f, 1.f}, { 0.f, 1.f, 0.f},
  { 1.f, 0.f, 0.f}, { 0.f, 0.f, 1.f}, { 0.f, 1.f, 0.f},
  { 1.f, 0.f, 0.f}, { 0.f, 0.f, 1.f}, { 0.f, 1.f, 0.f},
  { 0.f, 1.f, 0.f}, { 0.f, 0.f,-1.f}, {-1.f, 0.f, 0.f},
  { 1.f, 0.f, 0.f}, { 0.f, 1.f, 0.f}, { 0.f, 0.f, 1.f},
  { 0.0494f, 0.0366f, 0.99810825f},
  {-0.01716099f, 0.99266564f,-0.11966796f},
  { 1.f, 0.f, 0.f}, { 0.f, 0.f,-1.f},
  { 0.f, 1.f, 0.f}, { 0.f, 0.f, 1.f}, { 1.f, 0.f, 0.f},
  { 1.f, 0.f, 0.f}, { 0.f, 1.f, 0.f}, { 0.f, 0.f, 1.f},
  {-0.0494f,-0.0366f, 0.99810825f},
  { 0.01716099f,-0.99266564f,-0.11966796f},
  {-1.f, 0.f, 0.f}, { 0.f, 0.f,-1.f},
  { 0.f, 0.f, 0.f}
};
__constant__ int c_ridx[24][3] = {
  {0,1,2},{3,4,5},{6,46,46},{7,46,46},{8,46,46},{9,46,46},
  {10,11,12},{13,46,46},{14,46,46},{15,46,46},{16,46,46},
  {17,18,19},{20,21,22},{23,24,25},{26,27,28},{29,30,31},
  {32,46,46},{33,46,46},{34,35,46},{36,37,38},{39,40,41},
  {42,46,46},{43,46,46},{44,45,46}
};
__constant__ int c_par[24] = {-1,0,1,2,3,4,0,6,7,8,9,0,11,12,12,14,15,16,17,12,19,20,21,22};

__device__ __forceinline__ void mm3(const float* A, const float* Bm, float* C) {
#pragma unroll
  for (int i = 0; i < 3; ++i)
#pragma unroll
    for (int j = 0; j < 3; ++j)
      C[i*3+j] = A[i*3+0]*Bm[0+j] + A[i*3+1]*Bm[3+j] + A[i*3+2]*Bm[6+j];
}
__device__ __forceinline__ void mm3_bt(const float* A, const float* Bm, float* C) {
#pragma unroll
  for (int i = 0; i < 3; ++i)
#pragma unroll
    for (int j = 0; j < 3; ++j)
      C[i*3+j] = A[i*3+0]*Bm[j*3+0] + A[i*3+1]*Bm[j*3+1] + A[i*3+2]*Bm[j*3+2];
}

// ---- K0: static prep (R10-proven): pdm B-frags + smf hi/lo B-frags + jts zero ----
__global__ __launch_bounds__(256) void k0_prep(const float* __restrict__ posed,
                                               const float* __restrict__ sd,
                                               const float* __restrict__ vt,
                                               const float* __restrict__ sw,
                                               unsigned short* __restrict__ pdm,
                                               unsigned short* __restrict__ smf,
                                               float* __restrict__ jts) {
  const int lane = threadIdx.x & 63;
  if (blockIdx.x < 2268) {
    int tile = blockIdx.x * 4 + (threadIdx.x >> 6);   // 0..9071
    int kt = tile % NKT;
    int vtg = (tile / NKT) % NVT;
    int c  = tile / (NKT * NVT);
    int v  = vtg*16 + (lane & 15);
    int kb = kt*32 + (lane >> 4)*8;
    unsigned short vals[8];
#pragma unroll
    for (int j = 0; j < 8; ++j) {
      int k = kb + j;
      float f = 0.f;
      if (v < V_) {
        if (k < 207)       f = posed[(v*3 + c)*207 + k];
        else if (k < 217)  f = sd[(v*3 + c)*10 + (k - 207)];
        else if (k == 217) f = vt[v*3 + c];
      }
      vals[j] = f2bf(f);
    }
    *(uint4*)(pdm + (size_t)tile*512 + lane*8) = *(const uint4*)vals;
  } else {
    if (blockIdx.x == 2268) {
      for (int i = threadIdx.x; i < 24*33; i += 256) jts[i] = 0.f;
    }
    int tile = (blockIdx.x - 2268) * 4 + (threadIdx.x >> 6);  // 0..863
    int slot = tile & 1;
    int vtg  = tile >> 1;
    int v = vtg*16 + (lane & 15);
    int j0 = (lane >> 4) * 8;
    unsigned short vals[8];
#pragma unroll
    for (int jj = 0; jj < 8; ++jj) {
      int j = j0 + jj;
      float s = (v < V_ && j < NJ) ? sw[v*NJ + j] : 0.f;
      unsigned short hi = f2bf(s);
      vals[jj] = slot ? f2bf(s - bf2f(hi)) : hi;
    }
    *(uint4*)(smf + (size_t)tile*512 + lane*8) = *(const uint4*)vals;
  }
}

// ---- K1: jts via 8-way V-split + atomicAdd (R10-proven) ----
__global__ __launch_bounds__(256) void k1_jts(const float* __restrict__ jreg,
                                              const float* __restrict__ vt,
                                              const float* __restrict__ sd,
                                              float* __restrict__ jts) {
  const int j = blockIdx.x % 24;
  const int chunk = blockIdx.x / 24;
  const int v0 = chunk * 864;
  const int v1 = (v0 + 864 < V_) ? v0 + 864 : V_;
  float acc[3][11];
#pragma unroll
  for (int c = 0; c < 3; ++c)
#pragma unroll
    for (int i = 0; i < 11; ++i) acc[c][i] = 0.f;
  for (int v = v0 + threadIdx.x; v < v1; v += 256) {
    float wgt = jreg[j*V_ + v];
#pragma unroll
    for (int c = 0; c < 3; ++c) {
      acc[c][0] += wgt * vt[v*3 + c];
      const float* s = sd + (v*3 + c)*10;
#pragma unroll
      for (int k = 0; k < 10; ++k) acc[c][1+k] += wgt * s[k];
    }
  }
#pragma unroll
  for (int c = 0; c < 3; ++c)
#pragma unroll
    for (int i = 0; i < 11; ++i)
#pragma unroll
      for (int o = 32; o > 0; o >>= 1) acc[c][i] += __shfl_xor(acc[c][i], o, 64);
  __shared__ float red[4][33];
  int wid = threadIdx.x >> 6, ln = threadIdx.x & 63;
  if (ln == 0) {
#pragma unroll
    for (int c = 0; c < 3; ++c)
#pragma unroll
      for (int i = 0; i < 11; ++i) red[wid][c*11+i] = acc[c][i];
  }
  __syncthreads();
  if (threadIdx.x < 33) {
    float s = red[0][threadIdx.x] + red[1][threadIdx.x] +
              red[2][threadIdx.x] + red[3][threadIdx.x];
    atomicAdd(&jts[j*33 + threadIdx.x], s);
  }
}

// ---- kB: pose math + DIRECT frag emission (R8-proven form; mmf single-slot now) ----
// 512 blocks x 64 thr, one batch/block. batch b owns lanes {b&15 + 16h}.
__global__ __launch_bounds__(64) void kB_pose(const float* __restrict__ poses,
                                              const float* __restrict__ betas,
                                              const float* __restrict__ trans,
                                              const float* __restrict__ apose,
                                              const float* __restrict__ pjr,
                                              const float* __restrict__ jts,
                                              unsigned short* __restrict__ fmf,
                                              unsigned short* __restrict__ mmf) {
  const int b   = blockIdx.x;
  const int bt  = b >> 4;
  const int bl2 = b & 15;
  const int tl  = threadIdx.x;
  __shared__ float Rd[47][9];
  __shared__ float Rj[24][9];
  __shared__ float Rl[24][9];
  __shared__ float jl[24][3];
  __shared__ float G[24][12];

  if (tl < 47) {
    float q  = (tl < NP) ? poses[b*NP + tl] : 0.f;
    float ax = c_axes[tl][0], ay = c_axes[tl][1], az = c_axes[tl][2];
    float s = sinf(q), cq = cosf(q);
    float u = 1.f - cq;
    Rd[tl][0] = u*ax*ax + cq;   Rd[tl][1] = u*ax*ay - s*az; Rd[tl][2] = u*ax*az + s*ay;
    Rd[tl][3] = u*ax*ay + s*az; Rd[tl][4] = u*ay*ay + cq;   Rd[tl][5] = u*ay*az - s*ax;
    Rd[tl][6] = u*ax*az - s*ay; Rd[tl][7] = u*ay*az + s*ax; Rd[tl][8] = u*az*az + cq;
  }
  __syncthreads();
  if (tl < NJ) {
    const float* jr = jts + tl*33;
#pragma unroll
    for (int c = 0; c < 3; ++c) {
      float a = jr[c*11];
#pragma unroll
      for (int k = 0; k < 10; ++k) a += jr[c*11 + 1 + k] * betas[b*10 + k];
      jl[tl][c] = a;
    }
    float C1[9], C2[9];
    const int r0 = c_ridx[tl][0], r1 = c_ridx[tl][1], r2 = c_ridx[tl][2];
    mm3(&Rd[r0][0], &Rd[r1][0], C1);
    mm3(C1, &Rd[r2][0], C2);                 // Rj
#pragma unroll
    for (int e = 0; e < 9; ++e) Rj[tl][e] = C2[e];
    float P[9], Ap[9];
#pragma unroll
    for (int e = 0; e < 9; ++e) { P[e] = pjr[tl*9 + e]; Ap[e] = apose[tl*9 + e]; }
    mm3(P, C2, C1);
    mm3_bt(C1, P, C2);
    mm3(Ap, C2, C1);
#pragma unroll
    for (int e = 0; e < 9; ++e) Rl[tl][e] = C1[e];
  }
  __syncthreads();
  if (tl == 0) {                             // FK (serial, tiny)
#pragma unroll
    for (int e = 0; e < 9; ++e) G[0][e] = Rl[0][e];
    G[0][9] = jl[0][0]; G[0][10] = jl[0][1]; G[0][11] = jl[0][2];
    for (int j = 1; j < NJ; ++j) {
      int p = c_par[j];
      float R[9];
      mm3(&G[p][0], &Rl[j][0], R);
#pragma unroll
      for (int e = 0; e < 9; ++e) G[j][e] = R[e];
      float d0 = jl[j][0]-jl[p][0], d1 = jl[j][1]-jl[p][1], d2 = jl[j][2]-jl[p][2];
      G[j][9]  = G[p][9]  + G[p][0]*d0 + G[p][1]*d1 + G[p][2]*d2;
      G[j][10] = G[p][10] + G[p][3]*d0 + G[p][4]*d1 + G[p][5]*d2;
      G[j][11] = G[p][11] + G[p][6]*d0 + G[p][7]*d1 + G[p][8]*d2;
    }
  }
  __syncthreads();
  if (tl < NJ) {                             // A_t in place (+trans)
    float jx = jl[tl][0], jy = jl[tl][1], jz = jl[tl][2];
    float tx = trans[b*3+0], ty = trans[b*3+1], tz = trans[b*3+2];
    float a0 = G[tl][9]  - (G[tl][0]*jx + G[tl][1]*jy + G[tl][2]*jz) + tx;
    float a1 = G[tl][10] - (G[tl][3]*jx + G[tl][4]*jy + G[tl][5]*jz) + ty;
    float a2 = G[tl][11] - (G[tl][6]*jx + G[tl][7]*jy + G[tl][8]*jz) + tz;
    G[tl][9] = a0; G[tl][10] = a1; G[tl][11] = a2;
  }
  __syncthreads();

  // direct frag emission: 28 fmf tasks (kt,h) + 48 mmf tasks (e,h) [single hi slot]
  for (int task = tl; task < 76; task += 64) {
    if (task < 28) {
      int kt = task >> 2, h = task & 3;
      int ln = bl2 + 16*h;
      unsigned short vals[8];
#pragma unroll
      for (int j = 0; j < 8; ++j) {
        int k = kt*32 + h*8 + j;
        float val;
        if (k < 207) {
          int jj = k / 9 + 1, e = k % 9;
          val = Rj[jj][e] - ((e == 0 || e == 4 || e == 8) ? 1.f : 0.f);
        } else if (k < 217) val = betas[b*10 + (k - 207)];
        else if (k == 217)  val = 1.f;
        else                val = 0.f;
        vals[j] = f2bf(val);
      }
      *(uint4*)(fmf + ((size_t)bt*NKT + kt)*512 + ln*8) = *(const uint4*)vals;
    } else {
      int m = task - 28;          // 0..47
      int e = m >> 2;             // 0..11
      int h = m & 3;              // 0..3
      int ln = bl2 + 16*h;
      int j0 = h*8;
      unsigned short vals[8];
#pragma unroll
      for (int jj = 0; jj < 8; ++jj) {
        int j = j0 + jj;
        float f = (j < NJ) ? G[j][e] : 0.f;
        vals[jj] = f2bf(f);
      }
      *(uint4*)(mmf + ((size_t)e*NBT + bt)*512 + ln*8) = *(const uint4*)vals;
    }
  }
}

// ---- K3: GEMM1 + GEMM2 (2-term: mh·sh + mh·sl) + combine ----
__global__ __launch_bounds__(512) void k3_verts(
    const unsigned short* __restrict__ pdm,  // [3][432][7][512]
    const unsigned short* __restrict__ fmf,  // [32][7][512]
    const unsigned short* __restrict__ smf,  // [432][2][512]
    const unsigned short* __restrict__ mmf,  // [12][32][512]  (hi only)
    float* __restrict__ out)                 // [B][V][3]
{
  const int wg   = (blockIdx.x & 7) * 54 + (blockIdx.x >> 3);
  const int bt_blk = wg & 7;
  const int vt_blk = wg >> 3;
  const int t    = threadIdx.x;
  const int lane = t & 63;
  const int w    = t >> 6;
  const int wv   = w >> 1, wb = w & 1;
  const int vtg0 = vt_blk*8 + wv*2;
  const int btg0 = bt_blk*4 + wb*2;

  s16x8 sh[2], sl[2];
#pragma unroll
  for (int vs = 0; vs < 2; ++vs) {
    sh[vs] = *(const s16x8*)(smf + ((size_t)(vtg0+vs)*2 + 0)*512 + lane*8);
    sl[vs] = *(const s16x8*)(smf + ((size_t)(vtg0+vs)*2 + 1)*512 + lane*8);
  }

  f32x4 acc1[2][2][3];
#pragma unroll
  for (int vs = 0; vs < 2; ++vs)
#pragma unroll
    for (int bs = 0; bs < 2; ++bs)
#pragma unroll
      for (int c = 0; c < 3; ++c) acc1[vs][bs][c] = (f32x4){0.f,0.f,0.f,0.f};

#pragma unroll 1
  for (int kt = 0; kt < NKT; ++kt) {
    s16x8 fa[2], pb[2][3];
#pragma unroll
    for (int bs = 0; bs < 2; ++bs)
      fa[bs] = *(const s16x8*)(fmf + ((size_t)(btg0+bs)*NKT + kt)*512 + lane*8);
#pragma unroll
    for (int vs = 0; vs < 2; ++vs)
#pragma unroll
      for (int c = 0; c < 3; ++c)
        pb[vs][c] = *(const s16x8*)(pdm + (((size_t)c*NVT + vtg0+vs)*NKT + kt)*512 + lane*8);
#pragma unroll
    for (int vs = 0; vs < 2; ++vs)
#pragma unroll
      for (int bs = 0; bs < 2; ++bs)
#pragma unroll
        for (int c = 0; c < 3; ++c)
          acc1[vs][bs][c] = __builtin_amdgcn_mfma_f32_16x16x32_bf16(fa[bs], pb[vs][c], acc1[vs][bs][c], 0, 0, 0);
  }

  f32x4 vo[2][2][3];
#pragma unroll
  for (int vs = 0; vs < 2; ++vs)
#pragma unroll
    for (int bs = 0; bs < 2; ++bs)
#pragma unroll
      for (int m = 0; m < 3; ++m) vo[vs][bs][m] = (f32x4){0.f,0.f,0.f,0.f};

#pragma unroll
  for (int e = 0; e < 12; ++e) {
    s16x8 mh[2];
#pragma unroll
    for (int bs = 0; bs < 2; ++bs)
      mh[bs] = *(const s16x8*)(mmf + ((size_t)e*NBT + btg0+bs)*512 + lane*8);
#pragma unroll
    for (int vs = 0; vs < 2; ++vs)
#pragma unroll
      for (int bs = 0; bs < 2; ++bs) {
        f32x4 tmp = (f32x4){0.f,0.f,0.f,0.f};
        tmp = __builtin_amdgcn_mfma_f32_16x16x32_bf16(mh[bs], sh[vs], tmp, 0, 0, 0);
        tmp = __builtin_amdgcn_mfma_f32_16x16x32_bf16(mh[bs], sl[vs], tmp, 0, 0, 0);
        if (e < 9) vo[vs][bs][e/3] += tmp * acc1[vs][bs][e%3];
        else       vo[vs][bs][e-9] += tmp;
      }
  }

#pragma unroll
  for (int vs = 0; vs < 2; ++vs) {
    const int v = (vtg0+vs)*16 + (lane & 15);
    if (v < V_) {
#pragma unroll
      for (int bs = 0; bs < 2; ++bs) {
        const int b0 = (btg0+bs)*16 + (lane >> 4)*4;
#pragma unroll
        for (int q = 0; q < 4; ++q) {
          float* op = out + ((size_t)(b0 + q)*V_ + v)*3;
          op[0] = vo[vs][bs][0][q];
          op[1] = vo[vs][bs][1][q];
          op[2] = vo[vs][bs][2][q];
        }
      }
    }
  }
}

extern "C" void kernel_launch(void* const* d_in, const int* in_sizes, int n_in,
                              void* d_out, int out_size, void* d_ws, size_t ws_size,
                              hipStream_t stream) {
  (void)in_sizes; (void)n_in; (void)out_size; (void)ws_size;
  const float* betas      = (const float*)d_in[0];
  const float* poses      = (const float*)d_in[1];
  const float* trans      = (const float*)d_in[2];
  const float* v_template = (const float*)d_in[3];
  const float* shapedirs  = (const float*)d_in[4];
  const float* posedirs   = (const float*)d_in[5];
  const float* jreg       = (const float*)d_in[6];
  const float* skinw      = (const float*)d_in[7];
  const float* apose      = (const float*)d_in[8];
  const float* pjr        = (const float*)d_in[9];
  float* out = (float*)d_out;
  float* ws  = (float*)d_ws;

  unsigned short* pdm = (unsigned short*)ws;              // 9072*512 u16 = 2,322,432 f32
  unsigned short* fmf = (unsigned short*)(ws + 2322432);  // 224*512 u16  =    57,344 f32
  unsigned short* smf = (unsigned short*)(ws + 2379776);  // 864*512 u16  =   221,184 f32
  unsigned short* mmf = (unsigned short*)(ws + 2600960);  // 384*512 u16  =    98,304 f32
  float* jts = ws + 2699264;                              // 24*33 = 792

  hipLaunchKernelGGL(k0_prep, dim3(2484), dim3(256), 0, stream,
                     posedirs, shapedirs, v_template, skinw, pdm, smf, jts);
  hipLaunchKernelGGL(k1_jts, dim3(24*8), dim3(256), 0, stream,
                     jreg, v_template, shapedirs, jts);
  hipLaunchKernelGGL(kB_pose, dim3(B_), dim3(64), 0, stream,
                     poses, betas, trans, apose, pjr, jts, fmf, mmf);
  hipLaunchKernelGGL(k3_verts, dim3(432), dim3(512), 0, stream,
                     pdm, fmf, smf, mmf, out);
}

// Round 14
// 59.406 us; speedup vs baseline: 2.2586x; 1.0025x over previous
//
#include <hip/hip_runtime.h>
#include <cstdint>
#include <cstddef>

#define B_   512
#define V_   6890
#define VP   6912
#define NJ   24
#define KF   224
#define NP   46
#define NVT  432
#define NBT  32
#define NKT  7

typedef float f32x4 __attribute__((ext_vector_type(4)));
typedef short s16x8 __attribute__((ext_vector_type(8)));

__device__ __forceinline__ unsigned short f2bf(float f) {
  unsigned int u = __float_as_uint(f);
  u = (u + 0x7FFFu + ((u >> 16) & 1u)) >> 16;
  return (unsigned short)u;
}
__device__ __forceinline__ float bf2f(unsigned short h) {
  return __uint_as_float(((unsigned int)h) << 16);
}

__constant__ float c_axes[47][3] = {
  { 0.f, 0.f, 1.f}, { 1.f, 0.f, 0.f}, { 0.f, 1.f, 0.f},
  { 0.f, 0.f, 1.f}, { 1.f, 0.f, 0.f}, { 0.f, 1.f, 0.f},
  { 0.f, 0.f,-1.f},
  {-0.10501402f,-0.17402183f, 0.97912636f},
  { 0.78718019f, 0.60474702f,-0.12094817f},
  { 0.58095459f, 0.00000217f,-0.81393598f},
  { 0.f, 0.f, 1.f}, {-1.f, 0.f, 0.f}, { 0.f,-1.f, 0.f},
  { 0.f, 0.f,-1.f},
  {-0.10501402f,-0.17402183f, 0.97912636f},
  {-0.78718019f,-0.60474702f,-0.12094817f},
  {-0.58095459f, 0.00000217f,-0.81393598f},
  { 1.f, 0.f, 0.f}, { 0.f, 0.f, 1.f}, { 0.f, 1.f, 0.f},
  { 1.f, 0.f, 0.f}, { 0.f, 0.f, 1.f}, { 0.f, 1.f, 0.f},
  { 1.f, 0.f, 0.f}, { 0.f, 0.f, 1.f}, { 0.f, 1.f, 0.f},
  { 0.f, 1.f, 0.f}, { 0.f, 0.f,-1.f}, {-1.f, 0.f, 0.f},
  { 1.f, 0.f, 0.f}, { 0.f, 1.f, 0.f}, { 0.f, 0.f, 1.f},
  { 0.0494f, 0.0366f, 0.99810825f},
  {-0.01716099f, 0.99266564f,-0.11966796f},
  { 1.f, 0.f, 0.f}, { 0.f, 0.f,-1.f},
  { 0.f, 1.f, 0.f}, { 0.f, 0.f, 1.f}, { 1.f, 0.f, 0.f},
  { 1.f, 0.f, 0.f}, { 0.f, 1.f, 0.f}, { 0.f, 0.f, 1.f},
  {-0.0494f,-0.0366f, 0.99810825f},
  { 0.01716099f,-0.99266564f,-0.11966796f},
  {-1.f, 0.f, 0.f}, { 0.f, 0.f,-1.f},
  { 0.f, 0.f, 0.f}
};
__constant__ int c_ridx[24][3] = {
  {0,1,2},{3,4,5},{6,46,46},{7,46,46},{8,46,46},{9,46,46},
  {10,11,12},{13,46,46},{14,46,46},{15,46,46},{16,46,46},
  {17,18,19},{20,21,22},{23,24,25},{26,27,28},{29,30,31},
  {32,46,46},{33,46,46},{34,35,46},{36,37,38},{39,40,41},
  {42,46,46},{43,46,46},{44,45,46}
};
__constant__ int c_par[24] = {-1,0,1,2,3,4,0,6,7,8,9,0,11,12,12,14,15,16,17,12,19,20,21,22};

__device__ __forceinline__ void mm3(const float* A, const float* Bm, float* C) {
#pragma unroll
  for (int i = 0; i < 3; ++i)
#pragma unroll
    for (int j = 0; j < 3; ++j)
      C[i*3+j] = A[i*3+0]*Bm[0+j] + A[i*3+1]*Bm[3+j] + A[i*3+2]*Bm[6+j];
}
__device__ __forceinline__ void mm3_bt(const float* A, const float* Bm, float* C) {
#pragma unroll
  for (int i = 0; i < 3; ++i)
#pragma unroll
    for (int j = 0; j < 3; ++j)
      C[i*3+j] = A[i*3+0]*Bm[j*3+0] + A[i*3+1]*Bm[j*3+1] + A[i*3+2]*Bm[j*3+2];
}

// ---- K0: static prep (R10-proven): pdm B-frags + smf hi/lo B-frags + jts zero ----
__global__ __launch_bounds__(256) void k0_prep(const float* __restrict__ posed,
                                               const float* __restrict__ sd,
                                               const float* __restrict__ vt,
                                               const float* __restrict__ sw,
                                               unsigned short* __restrict__ pdm,
                                               unsigned short* __restrict__ smf,
                                               float* __restrict__ jts) {
  const int lane = threadIdx.x & 63;
  if (blockIdx.x < 2268) {
    int tile = blockIdx.x * 4 + (threadIdx.x >> 6);   // 0..9071
    int kt = tile % NKT;
    int vtg = (tile / NKT) % NVT;
    int c  = tile / (NKT * NVT);
    int v  = vtg*16 + (lane & 15);
    int kb = kt*32 + (lane >> 4)*8;
    unsigned short vals[8];
#pragma unroll
    for (int j = 0; j < 8; ++j) {
      int k = kb + j;
      float f = 0.f;
      if (v < V_) {
        if (k < 207)       f = posed[(v*3 + c)*207 + k];
        else if (k < 217)  f = sd[(v*3 + c)*10 + (k - 207)];
        else if (k == 217) f = vt[v*3 + c];
      }
      vals[j] = f2bf(f);
    }
    *(uint4*)(pdm + (size_t)tile*512 + lane*8) = *(const uint4*)vals;
  } else {
    if (blockIdx.x == 2268) {
      for (int i = threadIdx.x; i < 24*33; i += 256) jts[i] = 0.f;
    }
    int tile = (blockIdx.x - 2268) * 4 + (threadIdx.x >> 6);  // 0..863
    int slot = tile & 1;
    int vtg  = tile >> 1;
    int v = vtg*16 + (lane & 15);
    int j0 = (lane >> 4) * 8;
    unsigned short vals[8];
#pragma unroll
    for (int jj = 0; jj < 8; ++jj) {
      int j = j0 + jj;
      float s = (v < V_ && j < NJ) ? sw[v*NJ + j] : 0.f;
      unsigned short hi = f2bf(s);
      vals[jj] = slot ? f2bf(s - bf2f(hi)) : hi;
    }
    *(uint4*)(smf + (size_t)tile*512 + lane*8) = *(const uint4*)vals;
  }
}

// ---- K1: jts via 8-way V-split + atomicAdd (R10-proven) ----
__global__ __launch_bounds__(256) void k1_jts(const float* __restrict__ jreg,
                                              const float* __restrict__ vt,
                                              const float* __restrict__ sd,
                                              float* __restrict__ jts) {
  const int j = blockIdx.x % 24;
  const int chunk = blockIdx.x / 24;
  const int v0 = chunk * 864;
  const int v1 = (v0 + 864 < V_) ? v0 + 864 : V_;
  float acc[3][11];
#pragma unroll
  for (int c = 0; c < 3; ++c)
#pragma unroll
    for (int i = 0; i < 11; ++i) acc[c][i] = 0.f;
  for (int v = v0 + threadIdx.x; v < v1; v += 256) {
    float wgt = jreg[j*V_ + v];
#pragma unroll
    for (int c = 0; c < 3; ++c) {
      acc[c][0] += wgt * vt[v*3 + c];
      const float* s = sd + (v*3 + c)*10;
#pragma unroll
      for (int k = 0; k < 10; ++k) acc[c][1+k] += wgt * s[k];
    }
  }
#pragma unroll
  for (int c = 0; c < 3; ++c)
#pragma unroll
    for (int i = 0; i < 11; ++i)
#pragma unroll
      for (int o = 32; o > 0; o >>= 1) acc[c][i] += __shfl_xor(acc[c][i], o, 64);
  __shared__ float red[4][33];
  int wid = threadIdx.x >> 6, ln = threadIdx.x & 63;
  if (ln == 0) {
#pragma unroll
    for (int c = 0; c < 3; ++c)
#pragma unroll
      for (int i = 0; i < 11; ++i) red[wid][c*11+i] = acc[c][i];
  }
  __syncthreads();
  if (threadIdx.x < 33) {
    float s = red[0][threadIdx.x] + red[1][threadIdx.x] +
              red[2][threadIdx.x] + red[3][threadIdx.x];
    atomicAdd(&jts[j*33 + threadIdx.x], s);
  }
}

// ---- kB: pose math + DIRECT frag emission (R8-proven form; mmf single-slot now) ----
// 512 blocks x 64 thr, one batch/block. batch b owns lanes {b&15 + 16h}.
__global__ __launch_bounds__(64) void kB_pose(const float* __restrict__ poses,
                                              const float* __restrict__ betas,
                                              const float* __restrict__ trans,
                                              const float* __restrict__ apose,
                                              const float* __restrict__ pjr,
                                              const float* __restrict__ jts,
                                              unsigned short* __restrict__ fmf,
                                              unsigned short* __restrict__ mmf) {
  const int b   = blockIdx.x;
  const int bt  = b >> 4;
  const int bl2 = b & 15;
  const int tl  = threadIdx.x;
  __shared__ float Rd[47][9];
  __shared__ float Rj[24][9];
  __shared__ float Rl[24][9];
  __shared__ float jl[24][3];
  __shared__ float G[24][12];

  if (tl < 47) {
    float q  = (tl < NP) ? poses[b*NP + tl] : 0.f;
    float ax = c_axes[tl][0], ay = c_axes[tl][1], az = c_axes[tl][2];
    float s = sinf(q), cq = cosf(q);
    float u = 1.f - cq;
    Rd[tl][0] = u*ax*ax + cq;   Rd[tl][1] = u*ax*ay - s*az; Rd[tl][2] = u*ax*az + s*ay;
    Rd[tl][3] = u*ax*ay + s*az; Rd[tl][4] = u*ay*ay + cq;   Rd[tl][5] = u*ay*az - s*ax;
    Rd[tl][6] = u*ax*az - s*ay; Rd[tl][7] = u*ay*az + s*ax; Rd[tl][8] = u*az*az + cq;
  }
  __syncthreads();
  if (tl < NJ) {
    const float* jr = jts + tl*33;
#pragma unroll
    for (int c = 0; c < 3; ++c) {
      float a = jr[c*11];
#pragma unroll
      for (int k = 0; k < 10; ++k) a += jr[c*11 + 1 + k] * betas[b*10 + k];
      jl[tl][c] = a;
    }
    float C1[9], C2[9];
    const int r0 = c_ridx[tl][0], r1 = c_ridx[tl][1], r2 = c_ridx[tl][2];
    mm3(&Rd[r0][0], &Rd[r1][0], C1);
    mm3(C1, &Rd[r2][0], C2);                 // Rj
#pragma unroll
    for (int e = 0; e < 9; ++e) Rj[tl][e] = C2[e];
    float P[9], Ap[9];
#pragma unroll
    for (int e = 0; e < 9; ++e) { P[e] = pjr[tl*9 + e]; Ap[e] = apose[tl*9 + e]; }
    mm3(P, C2, C1);
    mm3_bt(C1, P, C2);
    mm3(Ap, C2, C1);
#pragma unroll
    for (int e = 0; e < 9; ++e) Rl[tl][e] = C1[e];
  }
  __syncthreads();
  if (tl == 0) {                             // FK (serial, tiny)
#pragma unroll
    for (int e = 0; e < 9; ++e) G[0][e] = Rl[0][e];
    G[0][9] = jl[0][0]; G[0][10] = jl[0][1]; G[0][11] = jl[0][2];
    for (int j = 1; j < NJ; ++j) {
      int p = c_par[j];
      float R[9];
      mm3(&G[p][0], &Rl[j][0], R);
#pragma unroll
      for (int e = 0; e < 9; ++e) G[j][e] = R[e];
      float d0 = jl[j][0]-jl[p][0], d1 = jl[j][1]-jl[p][1], d2 = jl[j][2]-jl[p][2];
      G[j][9]  = G[p][9]  + G[p][0]*d0 + G[p][1]*d1 + G[p][2]*d2;
      G[j][10] = G[p][10] + G[p][3]*d0 + G[p][4]*d1 + G[p][5]*d2;
      G[j][11] = G[p][11] + G[p][6]*d0 + G[p][7]*d1 + G[p][8]*d2;
    }
  }
  __syncthreads();
  if (tl < NJ) {                             // A_t in place (+trans)
    float jx = jl[tl][0], jy = jl[tl][1], jz = jl[tl][2];
    float tx = trans[b*3+0], ty = trans[b*3+1], tz = trans[b*3+2];
    float a0 = G[tl][9]  - (G[tl][0]*jx + G[tl][1]*jy + G[tl][2]*jz) + tx;
    float a1 = G[tl][10] - (G[tl][3]*jx + G[tl][4]*jy + G[tl][5]*jz) + ty;
    float a2 = G[tl][11] - (G[tl][6]*jx + G[tl][7]*jy + G[tl][8]*jz) + tz;
    G[tl][9] = a0; G[tl][10] = a1; G[tl][11] = a2;
  }
  __syncthreads();

  // direct frag emission: 28 fmf tasks (kt,h) + 48 mmf tasks (e,h) [single hi slot]
  for (int task = tl; task < 76; task += 64) {
    if (task < 28) {
      int kt = task >> 2, h = task & 3;
      int ln = bl2 + 16*h;
      unsigned short vals[8];
#pragma unroll
      for (int j = 0; j < 8; ++j) {
        int k = kt*32 + h*8 + j;
        float val;
        if (k < 207) {
          int jj = k / 9 + 1, e = k % 9;
          val = Rj[jj][e] - ((e == 0 || e == 4 || e == 8) ? 1.f : 0.f);
        } else if (k < 217) val = betas[b*10 + (k - 207)];
        else if (k == 217)  val = 1.f;
        else                val = 0.f;
        vals[j] = f2bf(val);
      }
      *(uint4*)(fmf + ((size_t)bt*NKT + kt)*512 + ln*8) = *(const uint4*)vals;
    } else {
      int m = task - 28;          // 0..47
      int e = m >> 2;             // 0..11
      int h = m & 3;              // 0..3
      int ln = bl2 + 16*h;
      int j0 = h*8;
      unsigned short vals[8];
#pragma unroll
      for (int jj = 0; jj < 8; ++jj) {
        int j = j0 + jj;
        float f = (j < NJ) ? G[j][e] : 0.f;
        vals[jj] = f2bf(f);
      }
      *(uint4*)(mmf + ((size_t)e*NBT + bt)*512 + ln*8) = *(const uint4*)vals;
    }
  }
}

// ---- K3: GEMM1 + GEMM2 (2-term: mh·sh + mh·sl) + combine ----
__global__ __launch_bounds__(512) void k3_verts(
    const unsigned short* __restrict__ pdm,  // [3][432][7][512]
    const unsigned short* __restrict__ fmf,  // [32][7][512]
    const unsigned short* __restrict__ smf,  // [432][2][512]
    const unsigned short* __restrict__ mmf,  // [12][32][512]  (hi only)
    float* __restrict__ out)                 // [B][V][3]
{
  const int wg   = (blockIdx.x & 7) * 54 + (blockIdx.x >> 3);
  const int bt_blk = wg & 7;
  const int vt_blk = wg >> 3;
  const int t    = threadIdx.x;
  const int lane = t & 63;
  const int w    = t >> 6;
  const int wv   = w >> 1, wb = w & 1;
  const int vtg0 = vt_blk*8 + wv*2;
  const int btg0 = bt_blk*4 + wb*2;

  s16x8 sh[2], sl[2];
#pragma unroll
  for (int vs = 0; vs < 2; ++vs) {
    sh[vs] = *(const s16x8*)(smf + ((size_t)(vtg0+vs)*2 + 0)*512 + lane*8);
    sl[vs] = *(const s16x8*)(smf + ((size_t)(vtg0+vs)*2 + 1)*512 + lane*8);
  }

  f32x4 acc1[2][2][3];
#pragma unroll
  for (int vs = 0; vs < 2; ++vs)
#pragma unroll
    for (int bs = 0; bs < 2; ++bs)
#pragma unroll
      for (int c = 0; c < 3; ++c) acc1[vs][bs][c] = (f32x4){0.f,0.f,0.f,0.f};

#pragma unroll 1
  for (int kt = 0; kt < NKT; ++kt) {
    s16x8 fa[2], pb[2][3];
#pragma unroll
    for (int bs = 0; bs < 2; ++bs)
      fa[bs] = *(const s16x8*)(fmf + ((size_t)(btg0+bs)*NKT + kt)*512 + lane*8);
#pragma unroll
    for (int vs = 0; vs < 2; ++vs)
#pragma unroll
      for (int c = 0; c < 3; ++c)
        pb[vs][c] = *(const s16x8*)(pdm + (((size_t)c*NVT + vtg0+vs)*NKT + kt)*512 + lane*8);
#pragma unroll
    for (int vs = 0; vs < 2; ++vs)
#pragma unroll
      for (int bs = 0; bs < 2; ++bs)
#pragma unroll
        for (int c = 0; c < 3; ++c)
          acc1[vs][bs][c] = __builtin_amdgcn_mfma_f32_16x16x32_bf16(fa[bs], pb[vs][c], acc1[vs][bs][c], 0, 0, 0);
  }

  f32x4 vo[2][2][3];
#pragma unroll
  for (int vs = 0; vs < 2; ++vs)
#pragma unroll
    for (int bs = 0; bs < 2; ++bs)
#pragma unroll
      for (int m = 0; m < 3; ++m) vo[vs][bs][m] = (f32x4){0.f,0.f,0.f,0.f};

#pragma unroll
  for (int e = 0; e < 12; ++e) {
    s16x8 mh[2];
#pragma unroll
    for (int bs = 0; bs < 2; ++bs)
      mh[bs] = *(const s16x8*)(mmf + ((size_t)e*NBT + btg0+bs)*512 + lane*8);
#pragma unroll
    for (int vs = 0; vs < 2; ++vs)
#pragma unroll
      for (int bs = 0; bs < 2; ++bs) {
        f32x4 tmp = (f32x4){0.f,0.f,0.f,0.f};
        tmp = __builtin_amdgcn_mfma_f32_16x16x32_bf16(mh[bs], sh[vs], tmp, 0, 0, 0);
        tmp = __builtin_amdgcn_mfma_f32_16x16x32_bf16(mh[bs], sl[vs], tmp, 0, 0, 0);
        if (e < 9) vo[vs][bs][e/3] += tmp * acc1[vs][bs][e%3];
        else       vo[vs][bs][e-9] += tmp;
      }
  }

#pragma unroll
  for (int vs = 0; vs < 2; ++vs) {
    const int v = (vtg0+vs)*16 + (lane & 15);
    if (v < V_) {
#pragma unroll
      for (int bs = 0; bs < 2; ++bs) {
        const int b0 = (btg0+bs)*16 + (lane >> 4)*4;
#pragma unroll
        for (int q = 0; q < 4; ++q) {
          float* op = out + ((size_t)(b0 + q)*V_ + v)*3;
          op[0] = vo[vs][bs][0][q];
          op[1] = vo[vs][bs][1][q];
          op[2] = vo[vs][bs][2][q];
        }
      }
    }
  }
}

extern "C" void kernel_launch(void* const* d_in, const int* in_sizes, int n_in,
                              void* d_out, int out_size, void* d_ws, size_t ws_size,
                              hipStream_t stream) {
  (void)in_sizes; (void)n_in; (void)out_size; (void)ws_size;
  const float* betas      = (const float*)d_in[0];
  const float* poses      = (const float*)d_in[1];
  const float* trans      = (const float*)d_in[2];
  const float* v_template = (const float*)d_in[3];
  const float* shapedirs  = (const float*)d_in[4];
  const float* posedirs   = (const float*)d_in[5];
  const float* jreg       = (const float*)d_in[6];
  const float* skinw      = (const float*)d_in[7];
  const float* apose      = (const float*)d_in[8];
  const float* pjr        = (const float*)d_in[9];
  float* out = (float*)d_out;
  float* ws  = (float*)d_ws;

  unsigned short* pdm = (unsigned short*)ws;              // 9072*512 u16 = 2,322,432 f32
  unsigned short* fmf = (unsigned short*)(ws + 2322432);  // 224*512 u16  =    57,344 f32
  unsigned short* smf = (unsigned short*)(ws + 2379776);  // 864*512 u16  =   221,184 f32
  unsigned short* mmf = (unsigned short*)(ws + 2600960);  // 384*512 u16  =    98,304 f32
  float* jts = ws + 2699264;                              // 24*33 = 792

  hipLaunchKernelGGL(k0_prep, dim3(2484), dim3(256), 0, stream,
                     posedirs, shapedirs, v_template, skinw, pdm, smf, jts);
  hipLaunchKernelGGL(k1_jts, dim3(24*8), dim3(256), 0, stream,
                     jreg, v_template, shapedirs, jts);
  hipLaunchKernelGGL(kB_pose, dim3(B_), dim3(64), 0, stream,
                     poses, betas, trans, apose, pjr, jts, fmf, mmf);
  hipLaunchKernelGGL(k3_verts, dim3(432), dim3(512), 0, stream,
                     pdm, fmf, smf, mmf, out);
}